// Round 4
// baseline (132.057 us; speedup 1.0000x reference)
//
#include <hip/hip_runtime.h>
#include <hip/hip_cooperative_groups.h>

namespace cg = cooperative_groups;

// predictions: [B=64, T=8192, D=64] f32 ; start_timestamp: int32 scalar (device)
// loss = sum_{b, j in [s,s+L), d} (p[b,j+1,d]-p[b,j,d])^2 / B - 0.5
// L = 4096, INHERENT_NEIGHBORHOOD = 0.5

#define BATCH 64
#define TDIM  8192
#define DDIM  64
#define LWIN  4096

#define D4    16                     // float4 per row
#define TD4   (TDIM * D4)            // 131072 float4 per-batch full span

#define RCHAIN   8                   // rows per chain: 9 loads -> 8 diffs
#define NTHREADS 256
#define NBLOCKS  1024                // 262144 threads; 2 chains each = 524288 chains
#define NCHAINS  (LWIN / RCHAIN)     // 512 chains per (b, column)

__global__ __launch_bounds__(NTHREADS, 8) void nl_coop_kernel(
    const float4* __restrict__ pred, const int* __restrict__ s_ptr,
    float* __restrict__ out, float* __restrict__ partial) {
    const int s = *s_ptr;
    const int t    = blockIdx.x * NTHREADS + threadIdx.x;  // 0..262143
    const int c    = t & 15;                 // float4 column within row
    const int g    = t >> 4;                 // chain id (first of two)
    const int jblk = g & (NCHAINS - 1);      // row-block within window
    const int b    = g >> 9;                 // batch 0..31 (second chain: b+32)

    const float4* p = pred +
        ((size_t)b * TD4 + (size_t)(s + jblk * RCHAIN) * D4 + c);

    float acc = 0.0f;
    #pragma unroll
    for (int ch = 0; ch < 2; ++ch) {
        float4 a[RCHAIN + 1];
        #pragma unroll
        for (int i = 0; i <= RCHAIN; ++i) a[i] = p[i * D4];
        #pragma unroll
        for (int i = 0; i < RCHAIN; ++i) {
            const float dx = a[i + 1].x - a[i].x;
            const float dy = a[i + 1].y - a[i].y;
            const float dz = a[i + 1].z - a[i].z;
            const float dw = a[i + 1].w - a[i].w;
            acc += dx * dx + dy * dy + dz * dz + dw * dw;
        }
        p += (size_t)32 * TD4;               // batches 32..63 on second pass
    }

    // wave64 reduce
    #pragma unroll
    for (int off = 32; off > 0; off >>= 1) acc += __shfl_down(acc, off, 64);

    __shared__ float smem[NTHREADS / 64];
    const int lane = threadIdx.x & 63;
    const int wid  = threadIdx.x >> 6;
    if (lane == 0) smem[wid] = acc;
    __syncthreads();
    if (threadIdx.x == 0) {
        const float bs = smem[0] + smem[1] + smem[2] + smem[3];
        atomicExch(&partial[blockIdx.x], bs);   // device-coherent store (cross-XCD)
    }

    cg::this_grid().sync();

    if (blockIdx.x == 0) {
        // 1024 partials, 256 threads -> one float4 each
        const float4* p4 = (const float4*)partial;
        const float4 v = p4[threadIdx.x];
        float a2 = v.x + v.y + v.z + v.w;
        #pragma unroll
        for (int off = 32; off > 0; off >>= 1) a2 += __shfl_down(a2, off, 64);
        __shared__ float smem2[NTHREADS / 64];
        if (lane == 0) smem2[wid] = a2;
        __syncthreads();
        if (threadIdx.x == 0) {
            const float total = smem2[0] + smem2[1] + smem2[2] + smem2[3];
            out[0] = total * (1.0f / BATCH) - 0.5f;  // INHERENT_NEIGHBORHOOD
        }
    }
}

extern "C" void kernel_launch(void* const* d_in, const int* in_sizes, int n_in,
                              void* d_out, int out_size, void* d_ws, size_t ws_size,
                              hipStream_t stream) {
    const float4* pred = (const float4*)d_in[0];
    const int* s_ptr   = (const int*)d_in[1];
    float* out         = (float*)d_out;
    float* partial     = (float*)d_ws;           // NBLOCKS floats = 4 KB

    void* args[] = {(void*)&pred, (void*)&s_ptr, (void*)&out, (void*)&partial};
    hipLaunchCooperativeKernel((const void*)nl_coop_kernel,
                               dim3(NBLOCKS), dim3(NTHREADS), args, 0, stream);
}

// Round 5
// 76.495 us; speedup vs baseline: 1.7263x; 1.7263x over previous
//
#include <hip/hip_runtime.h>

// predictions: [B=64, T=8192, D=64] f32 ; start_timestamp: int32 scalar (device)
// loss = sum_{b, j in [s,s+L), d} (p[b,j+1,d]-p[b,j,d])^2 / B - 0.5
// L = 4096, INHERENT_NEIGHBORHOOD = 0.5

#define BATCH 64
#define TDIM  8192
#define DDIM  64
#define LWIN  4096

#define D4    16                     // float4 per row
#define TD4   (TDIM * D4)            // 131072 float4 per-batch full span

#define RCHAIN   8                   // rows per chain: 9 loads -> 8 diffs
#define NTHREADS 256
#define NCHAINS  (LWIN / RCHAIN)     // 512 chains per (b, column)
#define TOTTHR   (BATCH * D4 * NCHAINS)   // 524288 threads, 1 chain each
#define NBLOCKS  (TOTTHR / NTHREADS)      // 2048

// Module-scope completion counter: loaded as 0, and the last block resets it
// to 0 at the end of EVERY call -> every call sees identical state
// (deterministic; not touched by the harness's d_ws/d_out poisoning).
__device__ int nl_done_counter = 0;

__global__ __launch_bounds__(NTHREADS) void nl_fused_kernel(
    const float4* __restrict__ pred, const int* __restrict__ s_ptr,
    float* __restrict__ out, float* __restrict__ partial) {
    const int s   = *s_ptr;
    const int tid = blockIdx.x * NTHREADS + threadIdx.x;
    const int c    = tid & 15;          // float4 column within row
    const int g    = tid >> 4;          // chain id
    const int jblk = g & (NCHAINS - 1); // row-block within window
    const int b    = g >> 9;            // batch

    const float4* p = pred + ((size_t)b * TD4 + (size_t)(s + jblk * RCHAIN) * D4 + c);

    // 9 consecutive rows' float4 at column c (independent loads -> full MLP)
    float4 a[RCHAIN + 1];
    #pragma unroll
    for (int i = 0; i <= RCHAIN; ++i) a[i] = p[i * D4];

    float acc = 0.0f;
    #pragma unroll
    for (int i = 0; i < RCHAIN; ++i) {
        const float dx = a[i + 1].x - a[i].x;
        const float dy = a[i + 1].y - a[i].y;
        const float dz = a[i + 1].z - a[i].z;
        const float dw = a[i + 1].w - a[i].w;
        acc += dx * dx + dy * dy + dz * dz + dw * dw;
    }

    // wave64 reduce
    #pragma unroll
    for (int off = 32; off > 0; off >>= 1) acc += __shfl_down(acc, off, 64);

    __shared__ float smem[NTHREADS / 64];
    __shared__ int is_last;
    const int lane = threadIdx.x & 63;
    const int wid  = threadIdx.x >> 6;
    if (lane == 0) smem[wid] = acc;
    __syncthreads();

    if (threadIdx.x == 0) {
        const float bs = smem[0] + smem[1] + smem[2] + smem[3];
        atomicExch(&partial[blockIdx.x], bs);    // device-coherent store (cross-XCD)
        __threadfence();                         // release: partial visible first
        const int old = atomicAdd(&nl_done_counter, 1);
        is_last = (old == NBLOCKS - 1) ? 1 : 0;
    }
    __syncthreads();

    if (is_last) {
        __threadfence();                         // acquire
        // 2048 partials / 256 threads = 8 each
        volatile const float* vp = partial;
        float a2 = 0.0f;
        #pragma unroll
        for (int i = 0; i < NBLOCKS / NTHREADS; ++i)
            a2 += vp[threadIdx.x + i * NTHREADS];
        #pragma unroll
        for (int off = 32; off > 0; off >>= 1) a2 += __shfl_down(a2, off, 64);
        __shared__ float smem2[NTHREADS / 64];
        if (lane == 0) smem2[wid] = a2;
        __syncthreads();
        if (threadIdx.x == 0) {
            const float total = smem2[0] + smem2[1] + smem2[2] + smem2[3];
            out[0] = total * (1.0f / BATCH) - 0.5f;  // INHERENT_NEIGHBORHOOD
            atomicExch(&nl_done_counter, 0);         // restore invariant for next call
        }
    }
}

extern "C" void kernel_launch(void* const* d_in, const int* in_sizes, int n_in,
                              void* d_out, int out_size, void* d_ws, size_t ws_size,
                              hipStream_t stream) {
    const float4* pred = (const float4*)d_in[0];
    const int* s_ptr   = (const int*)d_in[1];
    float* out         = (float*)d_out;
    float* partial     = (float*)d_ws;           // NBLOCKS floats = 8 KB

    nl_fused_kernel<<<NBLOCKS, NTHREADS, 0, stream>>>(pred, s_ptr, out, partial);
}

// Round 6
// 34.482 us; speedup vs baseline: 3.8297x; 2.2184x over previous
//
#include <hip/hip_runtime.h>

// predictions: [B=64, T=8192, D=64] f32 ; start_timestamp: int32 scalar (device)
// loss = sum_{b, j in [s,s+L), d} (p[b,j+1,d]-p[b,j,d])^2 / B - 0.5
// L = 4096, INHERENT_NEIGHBORHOOD = 0.5

#define BATCH 64
#define TDIM  8192
#define DDIM  64
#define LWIN  4096

#define D4    16                     // float4 per row
#define TD4   (TDIM * D4)            // 131072 float4 per-batch full span

#define RCHAIN   8                   // rows per chain: 9 loads -> 8 diffs
#define NTHREADS 256
#define NCHAINS  (LWIN / RCHAIN)     // 512 chains per (b, column)
#define TOTTHR   (BATCH * D4 * NCHAINS)   // 524288 threads, 1 chain each
#define NBLOCKS  (TOTTHR / NTHREADS)      // 2048

// Packed accumulator: bits [63:52] = completed-block count, bits [51:0] =
// fixed-point (2^-20) sum of squared diffs. One atomicAdd per block carries
// BOTH the partial sum and the "done" increment -> no fence, no ordering
// hazard (memory-side atomics are device-coherent), and integer adds commute
// exactly -> bit-deterministic output every call.
// Loaded as 0; the unique block that sees count==NBLOCKS resets it to 0,
// so every call (correctness, capture, replays) starts from identical state.
__device__ unsigned long long nl_acc = 0ULL;

#define CNT_SHIFT 52
#define SUM_MASK  ((1ULL << CNT_SHIFT) - 1ULL)
#define FIX_SCALE 1048576.0          // 2^20

__global__ __launch_bounds__(NTHREADS) void nl_fused_kernel(
    const float4* __restrict__ pred, const int* __restrict__ s_ptr,
    float* __restrict__ out) {
    const int s   = *s_ptr;
    const int tid = blockIdx.x * NTHREADS + threadIdx.x;
    const int c    = tid & 15;          // float4 column within row
    const int g    = tid >> 4;          // chain id
    const int jblk = g & (NCHAINS - 1); // row-block within window
    const int b    = g >> 9;            // batch

    const float4* p = pred + ((size_t)b * TD4 + (size_t)(s + jblk * RCHAIN) * D4 + c);

    // 9 consecutive rows' float4 at column c (independent loads -> full MLP)
    float4 a[RCHAIN + 1];
    #pragma unroll
    for (int i = 0; i <= RCHAIN; ++i) a[i] = p[i * D4];

    float acc = 0.0f;
    #pragma unroll
    for (int i = 0; i < RCHAIN; ++i) {
        const float dx = a[i + 1].x - a[i].x;
        const float dy = a[i + 1].y - a[i].y;
        const float dz = a[i + 1].z - a[i].z;
        const float dw = a[i + 1].w - a[i].w;
        acc += dx * dx + dy * dy + dz * dz + dw * dw;
    }

    // wave64 reduce
    #pragma unroll
    for (int off = 32; off > 0; off >>= 1) acc += __shfl_down(acc, off, 64);

    __shared__ float smem[NTHREADS / 64];
    const int lane = threadIdx.x & 63;
    const int wid  = threadIdx.x >> 6;
    if (lane == 0) smem[wid] = acc;
    __syncthreads();

    if (threadIdx.x == 0) {
        const float bs = smem[0] + smem[1] + smem[2] + smem[3];  // block sum (>= 0)
        const unsigned long long contrib =
            (1ULL << CNT_SHIFT) | (unsigned long long)((double)bs * FIX_SCALE);
        const unsigned long long old = atomicAdd(&nl_acc, contrib);
        const unsigned long long newv = old + contrib;
        if ((newv >> CNT_SHIFT) == (unsigned long long)NBLOCKS) {
            // I'm the last block: newv's low bits hold the COMPLETE sum.
            const double total = (double)(newv & SUM_MASK) * (1.0 / FIX_SCALE);
            out[0] = (float)(total * (1.0 / BATCH) - 0.5);  // INHERENT_NEIGHBORHOOD
            atomicExch(&nl_acc, 0ULL);   // restore invariant for the next call
        }
    }
}

extern "C" void kernel_launch(void* const* d_in, const int* in_sizes, int n_in,
                              void* d_out, int out_size, void* d_ws, size_t ws_size,
                              hipStream_t stream) {
    const float4* pred = (const float4*)d_in[0];
    const int* s_ptr   = (const int*)d_in[1];
    float* out         = (float*)d_out;

    nl_fused_kernel<<<NBLOCKS, NTHREADS, 0, stream>>>(pred, s_ptr, out);
}

// Round 7
// 16.962 us; speedup vs baseline: 7.7857x; 2.0329x over previous
//
#include <hip/hip_runtime.h>

// predictions: [B=64, T=8192, D=64] f32 ; start_timestamp: int32 scalar (device)
// loss = sum_{b, j in [s,s+L), d} (p[b,j+1,d]-p[b,j,d])^2 / B - 0.5
// L = 4096, INHERENT_NEIGHBORHOOD = 0.5

#define BATCH 64
#define TDIM  8192
#define DDIM  64
#define LWIN  4096

#define D4    16                     // float4 per row
#define TD4   (TDIM * D4)            // 131072 float4 per-batch full span

#define RCHAIN   8                   // rows per chain: 9 loads -> 8 diffs
#define NTHREADS 256
#define NCHAINS  (LWIN / RCHAIN)     // 512 chains per (b, column)
#define TOTTHR   (BATCH * D4 * NCHAINS)   // 524288 threads, 1 chain each
#define NBLOCKS  (TOTTHR / NTHREADS)      // 2048

// Hierarchical fence-free termination (R6 lesson: 2048 same-address atomics
// serialize at ~10ns each = +20us; spread them over 32 sub-counters).
// Each u64 packs: bits[63:52] = completed-block count, bits[51:0] = fixed-point
// (2^-20) partial sum. One atomicAdd carries both -> no fence, no ordering
// hazard; integer adds commute -> bit-deterministic. All counters load as 0
// and are restored to 0 by their unique "last" block every call.
#define NSUB      32
#define SUBPAD    8                   // 64B line padding between sub-counters
#define PER_SUB   (NBLOCKS / NSUB)    // 64 blocks per sub-counter
#define CNT_SHIFT 52
#define SUM_MASK  ((1ULL << CNT_SHIFT) - 1ULL)
#define FIX_SCALE 1048576.0           // 2^20

__device__ unsigned long long nl_sub[NSUB * SUBPAD] = {0};
__device__ unsigned long long nl_fin = 0ULL;

__global__ __launch_bounds__(NTHREADS) void nl_fused_kernel(
    const float4* __restrict__ pred, const int* __restrict__ s_ptr,
    float* __restrict__ out) {
    const int s   = *s_ptr;
    const int tid = blockIdx.x * NTHREADS + threadIdx.x;
    const int c    = tid & 15;          // float4 column within row
    const int g    = tid >> 4;          // chain id
    const int jblk = g & (NCHAINS - 1); // row-block within window
    const int b    = g >> 9;            // batch

    const float4* p = pred + ((size_t)b * TD4 + (size_t)(s + jblk * RCHAIN) * D4 + c);

    // 9 consecutive rows' float4 at column c (independent loads -> full MLP)
    float4 a[RCHAIN + 1];
    #pragma unroll
    for (int i = 0; i <= RCHAIN; ++i) a[i] = p[i * D4];

    float acc = 0.0f;
    #pragma unroll
    for (int i = 0; i < RCHAIN; ++i) {
        const float dx = a[i + 1].x - a[i].x;
        const float dy = a[i + 1].y - a[i].y;
        const float dz = a[i + 1].z - a[i].z;
        const float dw = a[i + 1].w - a[i].w;
        acc += dx * dx + dy * dy + dz * dz + dw * dw;
    }

    // wave64 reduce
    #pragma unroll
    for (int off = 32; off > 0; off >>= 1) acc += __shfl_down(acc, off, 64);

    __shared__ float smem[NTHREADS / 64];
    const int lane = threadIdx.x & 63;
    const int wid  = threadIdx.x >> 6;
    if (lane == 0) smem[wid] = acc;
    __syncthreads();

    if (threadIdx.x == 0) {
        const float bs = smem[0] + smem[1] + smem[2] + smem[3];  // block sum (>=0)
        const int sub = (blockIdx.x & (NSUB - 1)) * SUBPAD;
        const unsigned long long contrib =
            (1ULL << CNT_SHIFT) | (unsigned long long)((double)bs * FIX_SCALE);
        const unsigned long long oldv = atomicAdd(&nl_sub[sub], contrib);
        const unsigned long long newv = oldv + contrib;
        if ((newv >> CNT_SHIFT) == (unsigned long long)PER_SUB) {
            // last block of this sub-group: fold exact subtotal into final
            atomicExch(&nl_sub[sub], 0ULL);          // restore for next call
            const unsigned long long c2 =
                (1ULL << CNT_SHIFT) | (newv & SUM_MASK);
            const unsigned long long old2 = atomicAdd(&nl_fin, c2);
            const unsigned long long new2 = old2 + c2;
            if ((new2 >> CNT_SHIFT) == (unsigned long long)NSUB) {
                const double total = (double)(new2 & SUM_MASK) * (1.0 / FIX_SCALE);
                out[0] = (float)(total * (1.0 / BATCH) - 0.5);  // INHERENT_NEIGHBORHOOD
                atomicExch(&nl_fin, 0ULL);           // restore for next call
            }
        }
    }
}

extern "C" void kernel_launch(void* const* d_in, const int* in_sizes, int n_in,
                              void* d_out, int out_size, void* d_ws, size_t ws_size,
                              hipStream_t stream) {
    const float4* pred = (const float4*)d_in[0];
    const int* s_ptr   = (const int*)d_in[1];
    float* out         = (float*)d_out;

    nl_fused_kernel<<<NBLOCKS, NTHREADS, 0, stream>>>(pred, s_ptr, out);
}

// Round 8
// 16.858 us; speedup vs baseline: 7.8335x; 1.0061x over previous
//
#include <hip/hip_runtime.h>

// predictions: [B=64, T=8192, D=64] f32 ; start_timestamp: int32 scalar (device)
// loss = sum_{b, j in [s,s+L), d} (p[b,j+1,d]-p[b,j,d])^2 / B - 0.5
// L = 4096, INHERENT_NEIGHBORHOOD = 0.5

#define BATCH 64
#define TDIM  8192
#define DDIM  64
#define LWIN  4096

#define D4    16                     // float4 per row
#define TD4   (TDIM * D4)            // 131072 float4 per-batch full span

#define RCHAIN   8                   // rows per chain: 9 loads -> 8 diffs
#define NTHREADS 256
#define NCHAINS  (LWIN / RCHAIN)     // 512 chains per (b, column)
#define TOTTHR   (BATCH * D4 * NCHAINS)   // 524288 threads, 1 chain each
#define NBLOCKS  (TOTTHR / NTHREADS)      // 2048

// Hierarchical fence-free termination (R6: one hot counter = +20us; R7: 32
// sub-counters = ~1us). Each u64 packs bits[63:52]=count, bits[51:0]=fixed-
// point (2^-20) sum; one atomicAdd carries both -> no fence needed; integer
// adds commute -> bit-deterministic. All counters self-restore to 0.
#define NSUB      32
#define SUBPAD    8                   // 64B padding between sub-counters
#define PER_SUB   (NBLOCKS / NSUB)    // 64 blocks per sub-counter
#define CNT_SHIFT 52
#define SUM_MASK  ((1ULL << CNT_SHIFT) - 1ULL)
#define FIX_SCALE 1048576.0           // 2^20

__device__ unsigned long long nl_sub[NSUB * SUBPAD] = {0};
__device__ unsigned long long nl_fin = 0ULL;

__global__ __launch_bounds__(NTHREADS) void nl_fused_kernel(
    const float4* __restrict__ pred, const int* __restrict__ s_ptr,
    float* __restrict__ out) {
    const int s   = *s_ptr;
    const int tid = blockIdx.x * NTHREADS + threadIdx.x;
    const int c    = tid & 15;          // float4 column within row
    const int g    = tid >> 4;          // chain id
    const int jblk = g & (NCHAINS - 1); // row-block within window
    const int b    = g >> 9;            // batch

    const float4* p = pred + ((size_t)b * TD4 + (size_t)(s + jblk * RCHAIN) * D4 + c);

    // R7 lesson: with a[9] array the compiler minimized liveness (VGPR=20),
    // interleaving loads with diffs -> ~2 loads in flight -> latency-bound.
    // Named regs + sched_barrier(0) pin ALL 9 loads before ANY diff: full MLP.
    const float4 a0 = p[0 * D4];
    const float4 a1 = p[1 * D4];
    const float4 a2 = p[2 * D4];
    const float4 a3 = p[3 * D4];
    const float4 a4 = p[4 * D4];
    const float4 a5 = p[5 * D4];
    const float4 a6 = p[6 * D4];
    const float4 a7 = p[7 * D4];
    const float4 a8 = p[8 * D4];
    __builtin_amdgcn_sched_barrier(0);   // nothing crosses: loads all issue first

    float acc = 0.0f;
    {
        float dx, dy, dz, dw;
#define DIFF(lo, hi)                                                       \
        dx = hi.x - lo.x; dy = hi.y - lo.y;                                \
        dz = hi.z - lo.z; dw = hi.w - lo.w;                                \
        acc += dx * dx + dy * dy + dz * dz + dw * dw;
        DIFF(a0, a1) DIFF(a1, a2) DIFF(a2, a3) DIFF(a3, a4)
        DIFF(a4, a5) DIFF(a5, a6) DIFF(a6, a7) DIFF(a7, a8)
#undef DIFF
    }

    // wave64 reduce
    #pragma unroll
    for (int off = 32; off > 0; off >>= 1) acc += __shfl_down(acc, off, 64);

    __shared__ float smem[NTHREADS / 64];
    const int lane = threadIdx.x & 63;
    const int wid  = threadIdx.x >> 6;
    if (lane == 0) smem[wid] = acc;
    __syncthreads();

    if (threadIdx.x == 0) {
        const float bs = smem[0] + smem[1] + smem[2] + smem[3];  // block sum (>=0)
        const int sub = (blockIdx.x & (NSUB - 1)) * SUBPAD;
        const unsigned long long contrib =
            (1ULL << CNT_SHIFT) | (unsigned long long)((double)bs * FIX_SCALE);
        const unsigned long long oldv = atomicAdd(&nl_sub[sub], contrib);
        const unsigned long long newv = oldv + contrib;
        if ((newv >> CNT_SHIFT) == (unsigned long long)PER_SUB) {
            atomicExch(&nl_sub[sub], 0ULL);          // restore for next call
            const unsigned long long c2 =
                (1ULL << CNT_SHIFT) | (newv & SUM_MASK);
            const unsigned long long old2 = atomicAdd(&nl_fin, c2);
            const unsigned long long new2 = old2 + c2;
            if ((new2 >> CNT_SHIFT) == (unsigned long long)NSUB) {
                const double total = (double)(new2 & SUM_MASK) * (1.0 / FIX_SCALE);
                out[0] = (float)(total * (1.0 / BATCH) - 0.5);  // INHERENT_NEIGHBORHOOD
                atomicExch(&nl_fin, 0ULL);           // restore for next call
            }
        }
    }
}

extern "C" void kernel_launch(void* const* d_in, const int* in_sizes, int n_in,
                              void* d_out, int out_size, void* d_ws, size_t ws_size,
                              hipStream_t stream) {
    const float4* pred = (const float4*)d_in[0];
    const int* s_ptr   = (const int*)d_in[1];
    float* out         = (float*)d_out;

    nl_fused_kernel<<<NBLOCKS, NTHREADS, 0, stream>>>(pred, s_ptr, out);
}